// Round 8
// baseline (173.299 us; speedup 1.0000x reference)
//
#include <hip/hip_runtime.h>

// Problem constants (from reference)
#define NS     4096                 // N_SAMPLES
#define NW     64                   // N_WIDTH
#define NNODES 257                  // N_NODES
#define SW     (NS * NW)            // 262144
#define ROW    (NW * NNODES)        // 16448 floats per sample region
#define ROW4   (ROW / 4)            // 4112 float4 groups per sample region
#define SWN    ((size_t)NS * NW * NNODES)  // 67,371,008

typedef float v4f __attribute__((ext_vector_type(4)));   // native vector for nontemporal builtin

// Hard-coded Lagrange basis polynomials over nodes [-1,-0.5,0,0.5,1] (verified R4/R6).
// phi: Horner x^4..x^0; dphi pre-scaled by 128 (1/delta_x); ddphi by 16384.
__device__ __constant__ const float P4[5] = { (float)( 2.0/3.0), (float)(-8.0/3.0),  4.0f, (float)(-8.0/3.0), (float)( 2.0/3.0) };
__device__ __constant__ const float P3[5] = { (float)(-2.0/3.0), (float)( 4.0/3.0),  0.0f, (float)(-4.0/3.0), (float)( 2.0/3.0) };
__device__ __constant__ const float P2[5] = { (float)(-1.0/6.0), (float)( 8.0/3.0), -5.0f, (float)( 8.0/3.0), (float)(-1.0/6.0) };
__device__ __constant__ const float P1[5] = { (float)( 1.0/6.0), (float)(-4.0/3.0),  0.0f, (float)( 4.0/3.0), (float)(-1.0/6.0) };
__device__ __constant__ const float P0[5] = { 0.0f, 0.0f, 1.0f, 0.0f, 0.0f };

__device__ __constant__ const float D3[5] = { (float)( 1024.0/3.0), (float)(-4096.0/3.0),  2048.0f, (float)(-4096.0/3.0), (float)(1024.0/3.0) };
__device__ __constant__ const float D2[5] = { -256.0f, 512.0f, 0.0f, -512.0f, 256.0f };
__device__ __constant__ const float D1[5] = { (float)( -128.0/3.0), (float)( 2048.0/3.0), -1280.0f, (float)( 2048.0/3.0), (float)(-128.0/3.0) };
__device__ __constant__ const float D0[5] = { (float)(   64.0/3.0), (float)( -512.0/3.0),     0.0f, (float)(  512.0/3.0), (float)( -64.0/3.0) };

__device__ __constant__ const float E2[5] = { 131072.0f, -524288.0f, 786432.0f, -524288.0f, 131072.0f };
__device__ __constant__ const float E1[5] = { -65536.0f,  131072.0f,      0.0f, -131072.0f,  65536.0f };
__device__ __constant__ const float E0[5] = { (float)(-16384.0/3.0), (float)(262144.0/3.0), -163840.0f, (float)(262144.0/3.0), (float)(-16384.0/3.0) };

__device__ __forceinline__ void basis_all(float xi, int* b_out, float bas[3][5])
{
    const float xs = 256.0f * xi;
    float fel = floorf(xs * 0.25f);
    fel = fminf(fmaxf(fel, 0.0f), 63.0f);
    const int   b = (int)fel * 4;
    const float t = 0.5f * (xs - (float)b) - 1.0f;
    #pragma unroll
    for (int j = 0; j < 5; ++j) {
        bas[0][j] = (((P4[j]*t + P3[j])*t + P2[j])*t + P1[j])*t + P0[j];
        bas[1][j] = ((D3[j]*t + D2[j])*t + D1[j])*t + D0[j];
        bas[2][j] = (E2[j]*t + E1[j])*t + E0[j];
    }
    *b_out = b;
}

// ---------------------------------------------------------------------------
// K_A: per-sample record -> ws[i*16] = {phi[5], dphi[5], ddphi[5], (float)b}
// ---------------------------------------------------------------------------
__global__ __launch_bounds__(256) void k_basis(
    const float* __restrict__ x, float* __restrict__ ws)
{
    const int i = blockIdx.x * 256 + threadIdx.x;
    if (i >= NS) return;
    int b; float bas[3][5];
    basis_all(x[i], &b, bas);
    float* r = ws + (size_t)i * 16;
    #pragma unroll
    for (int j = 0; j < 5; ++j) {
        r[j]      = bas[0][j];
        r[5 + j]  = bas[1][j];
        r[10 + j] = bas[2][j];
    }
    r[15] = (float)b;
}

// ---------------------------------------------------------------------------
// K_B: dominant single-stream writer. block = (sample i, array a).
// ---------------------------------------------------------------------------
__global__ __launch_bounds__(256) void k_write(
    const float* __restrict__ ws, float* __restrict__ out)
{
    const int i   = blockIdx.x;
    const int a   = blockIdx.y;
    const int tid = threadIdx.x;

    const float* tb = ws + (size_t)i * 16;
    float ba[5];
    #pragma unroll
    for (int j = 0; j < 5; ++j) ba[j] = tb[a * 5 + j];
    const int b  = (int)tb[15];
    const int g0 = b >> 2;

    // hit precompute: nonzero groups om = 64*rho + g0 + p; this thread's
    // group o = tid + 256*n has om = (tid - n) mod 257 -> hit n = (tid-gm) mod 257 <= 16.
    int h0 = -1, h1 = -1;
    float w0[4] = {0.f,0.f,0.f,0.f}, w1[4] = {0.f,0.f,0.f,0.f};
    #pragma unroll
    for (int rho = 0; rho < 4; ++rho) {
        #pragma unroll
        for (int p = 0; p < 2; ++p) {
            const int gm = 64 * rho + g0 + p;
            int d = tid - gm;
            if (d < 0) d += 257;
            if (d < 17) {
                h1 = h0;
                #pragma unroll
                for (int c = 0; c < 4; ++c) w1[c] = w0[c];
                h0 = d;
                #pragma unroll
                for (int c = 0; c < 4; ++c) {
                    const int j = 4 * p + c - rho;     // compile-time constant
                    w0[c] = (j >= 0 && j <= 4) ? ba[j] : 0.0f;
                }
            }
        }
    }

    v4f* r = reinterpret_cast<v4f*>(
        out + 3 * (size_t)SW + (size_t)a * SWN + (size_t)i * ROW);

    #pragma unroll
    for (int n = 0; n < 16; ++n) {
        const int o = tid + (n << 8);
        float v[4];
        #pragma unroll
        for (int c = 0; c < 4; ++c) {
            const float t1 = (n == h1) ? w1[c] : 0.0f;
            v[c]           = (n == h0) ? w0[c] : t1;
        }
        const v4f val = { v[0], v[1], v[2], v[3] };
        __builtin_nontemporal_store(val, &r[o]);
    }
    if (tid < 16) {                                    // groups 4096..4111
        const int n = 16;
        const int o = tid + (n << 8);
        float v[4];
        #pragma unroll
        for (int c = 0; c < 4; ++c) {
            const float t1 = (n == h1) ? w1[c] : 0.0f;
            v[c]           = (n == h0) ? w0[c] : t1;
        }
        const v4f val = { v[0], v[1], v[2], v[3] };
        __builtin_nontemporal_store(val, &r[o]);
    }
}

// ---------------------------------------------------------------------------
// K_C: t/dt/ddt dots + delta_x. 4 samples per block, lane = width k.
// ---------------------------------------------------------------------------
__global__ __launch_bounds__(256) void k_dots(
    const float* __restrict__ ws, const float* __restrict__ weight,
    float* __restrict__ out)
{
    const int tid  = threadIdx.x;
    const int lane = tid & 63;
    const int i    = blockIdx.x * 4 + (tid >> 6);

    const float* tb = ws + (size_t)i * 16;
    const int b = (int)tb[15];
    const float* wrow = weight + lane * NNODES + b;

    float s0 = 0.0f, s1 = 0.0f, s2 = 0.0f;
    #pragma unroll
    for (int j = 0; j < 5; ++j) {
        const float w = wrow[j];
        s0 += w * tb[j];
        s1 += w * tb[5 + j];
        s2 += w * tb[10 + j];
    }
    out[(size_t)i * NW + lane]                  = s0;
    out[SW + (size_t)i * NW + lane]             = s1;
    out[2 * (size_t)SW + (size_t)i * NW + lane] = s2;

    if (blockIdx.x == 0 && tid == 0)
        out[3 * (size_t)SW + 3 * SWN] = 0.0078125f;   // delta_x
}

// ---------------------------------------------------------------------------
// Fallback: the R6 fused kernel (known-correct, 154.5 us) if ws is too small.
// ---------------------------------------------------------------------------
__global__ __launch_bounds__(256) void kann_all(
    const float* __restrict__ x, const float* __restrict__ weight,
    float* __restrict__ out)
{
    const int i   = blockIdx.x;
    const int tid = threadIdx.x;

    int b; float bas[3][5];
    basis_all(x[i], &b, bas);

    if (tid < NW) {
        const float* wrow = weight + tid * NNODES + b;
        float s0 = 0.0f, s1 = 0.0f, s2 = 0.0f;
        #pragma unroll
        for (int j = 0; j < 5; ++j) {
            const float w = wrow[j];
            s0 += w * bas[0][j]; s1 += w * bas[1][j]; s2 += w * bas[2][j];
        }
        out[(size_t)i * NW + tid]                  = s0;
        out[SW + (size_t)i * NW + tid]             = s1;
        out[2 * (size_t)SW + (size_t)i * NW + tid] = s2;
    }
    if (i == 0 && tid == 64) out[3 * (size_t)SW + 3 * SWN] = 0.0078125f;

    const int g0 = b >> 2;
    int h0 = -1, h1 = -1;
    float w0v[3][4], w1v[3][4];
    #pragma unroll
    for (int a = 0; a < 3; ++a)
        #pragma unroll
        for (int c = 0; c < 4; ++c) { w0v[a][c] = 0.0f; w1v[a][c] = 0.0f; }
    #pragma unroll
    for (int rho = 0; rho < 4; ++rho) {
        #pragma unroll
        for (int p = 0; p < 2; ++p) {
            const int gm = 64 * rho + g0 + p;
            int d = tid - gm;
            if (d < 0) d += 257;
            if (d < 17) {
                h1 = h0;
                #pragma unroll
                for (int a = 0; a < 3; ++a)
                    #pragma unroll
                    for (int c = 0; c < 4; ++c) w1v[a][c] = w0v[a][c];
                h0 = d;
                #pragma unroll
                for (int a = 0; a < 3; ++a)
                    #pragma unroll
                    for (int c = 0; c < 4; ++c) {
                        const int j = 4 * p + c - rho;
                        w0v[a][c] = (j >= 0 && j <= 4) ? bas[a][j] : 0.0f;
                    }
            }
        }
    }
    float* big = out + 3 * (size_t)SW + (size_t)i * ROW;
    float4* r0 = reinterpret_cast<float4*>(big);
    float4* r1 = reinterpret_cast<float4*>(big + SWN);
    float4* r2 = reinterpret_cast<float4*>(big + 2 * SWN);
    #pragma unroll
    for (int n = 0; n < 16; ++n) {
        const int o = tid + (n << 8);
        float v[3][4];
        #pragma unroll
        for (int a = 0; a < 3; ++a)
            #pragma unroll
            for (int c = 0; c < 4; ++c) {
                const float t1 = (n == h1) ? w1v[a][c] : 0.0f;
                v[a][c]        = (n == h0) ? w0v[a][c] : t1;
            }
        r0[o] = make_float4(v[0][0], v[0][1], v[0][2], v[0][3]);
        r1[o] = make_float4(v[1][0], v[1][1], v[1][2], v[1][3]);
        r2[o] = make_float4(v[2][0], v[2][1], v[2][2], v[2][3]);
    }
    if (tid < 16) {
        const int n = 16;
        const int o = tid + (n << 8);
        float v[3][4];
        #pragma unroll
        for (int a = 0; a < 3; ++a)
            #pragma unroll
            for (int c = 0; c < 4; ++c) {
                const float t1 = (n == h1) ? w1v[a][c] : 0.0f;
                v[a][c]        = (n == h0) ? w0v[a][c] : t1;
            }
        r0[o] = make_float4(v[0][0], v[0][1], v[0][2], v[0][3]);
        r1[o] = make_float4(v[1][0], v[1][1], v[1][2], v[1][3]);
        r2[o] = make_float4(v[2][0], v[2][1], v[2][2], v[2][3]);
    }
}

extern "C" void kernel_launch(void* const* d_in, const int* in_sizes, int n_in,
                              void* d_out, int out_size, void* d_ws, size_t ws_size,
                              hipStream_t stream) {
    const float* x      = (const float*)d_in[0];
    const float* weight = (const float*)d_in[1];
    float* out          = (float*)d_out;

    if (ws_size >= (size_t)NS * 16 * sizeof(float)) {
        float* ws = (float*)d_ws;
        k_basis<<<NS / 256, 256, 0, stream>>>(x, ws);
        dim3 g(NS, 3);
        k_write<<<g, 256, 0, stream>>>(ws, out);
        k_dots<<<NS / 4, 256, 0, stream>>>(ws, weight, out);
    } else {
        kann_all<<<NS, 256, 0, stream>>>(x, weight, out);
    }
}